// Round 11
// baseline (112.830 us; speedup 1.0000x reference)
//
#include <hip/hip_runtime.h>
#include <hip/hip_bf16.h>

// Problem constants (from reference setup_inputs)
#define B_  16
#define S_  1024
#define D_  300
#define K_  64           // hidden_set_size == compressed dim
#define O_  256          // outputs per batch
#define M_  (B_*S_)      // 16384 rows (b,s)

typedef __attribute__((ext_vector_type(8)))  short s8b;    // 8 x bf16 (4 VGPRs)
typedef __attribute__((ext_vector_type(4)))  float f32x4;
typedef __attribute__((ext_vector_type(16))) float f32x16;

#define MFMA16(a,b,c) __builtin_amdgcn_mfma_f32_16x16x32_bf16((a),(b),(c),0,0,0)
#define MFMA32(a,b,c) __builtin_amdgcn_mfma_f32_32x32x16_bf16((a),(b),(c),0,0,0)

__device__ __forceinline__ unsigned short bf16_bits(float f) {
    return __builtin_bit_cast(unsigned short, __float2bfloat16(f));
}
__device__ __forceinline__ float max3f(float a, float b, float c) {
    return fmaxf(fmaxf(a, b), c);              // -> v_max3_f32
}

// ---------------------------------------------------------------------------
// Fragment-major layouts (16B chunks, indexed as uint4):
//  XcF chunk[(mtile*4 + ks)*64 + half*32 + l31] = Xc[mtile*32+l31][ks*16+half*8 .. +7]
//      (exactly the B-fragment of mfma_32x32x16; mtile = global bs row / 32)
//  HbF chunk[o*512 + nt*256 + ks*64 + half*32 + l31] = H[o][nt*32+l31][ks*16+half*8 .. +7]
//      (exactly the A-fragment)
// In k_fused every fragment load is ONE dwordx4 over 1024 CONTIGUOUS bytes.
// ---------------------------------------------------------------------------

// ---------------------------------------------------------------------------
// Kernel 1 (k_prep):
//   blocks [0, 512)    : compress GEMM for one 32-row m-tile ->
//                        bf16(Xs @ W^T + b), transposed to frag-major XcF
//                        via a padded LDS bounce (32 x 72 elements).
//   blocks [512, 1024) : H f32 -> frag-major HbF, 8 el/thread, coalesced.
// ---------------------------------------------------------------------------
#define C_BLK 512
#define H_BLK 512     // 256*64*64/8/256
#define LT    72      // LDS transpose row stride (elements; 144 B, 16B-aligned)

__global__ __launch_bounds__(256) void k_prep(
        const float* __restrict__ Xs, const float* __restrict__ W,
        const float* __restrict__ bias, const float* __restrict__ H,
        __hip_bfloat16* __restrict__ XcF, __hip_bfloat16* __restrict__ HbF) {
    __shared__ __hip_bfloat16 lt[32 * LT];     // 4608 B
    int bx = blockIdx.x, tid = threadIdx.x;

    if (bx >= C_BLK) {                         // ---- H -> HbF (frag-major) ----
        int g8 = (bx - C_BLK) * 256 + tid;     // 8-element group index
        const float* src = H + (size_t)g8 * 8;
        float4 f0 = *(const float4*)(src);
        float4 f1 = *(const float4*)(src + 4);
        union { unsigned short us[8]; uint4 q; } pk;
        pk.us[0]=bf16_bits(f0.x); pk.us[1]=bf16_bits(f0.y);
        pk.us[2]=bf16_bits(f0.z); pk.us[3]=bf16_bits(f0.w);
        pk.us[4]=bf16_bits(f1.x); pk.us[5]=bf16_bits(f1.y);
        pk.us[6]=bf16_bits(f1.z); pk.us[7]=bf16_bits(f1.w);
        int k8 = g8 & 7, n = (g8 >> 3) & 63, o = g8 >> 9;
        int idx = o * 512 + (n >> 5) * 256 + (k8 >> 1) * 64
                + (k8 & 1) * 32 + (n & 31);
        ((uint4*)HbF)[idx] = pk.q;             // 8 full 128B lines per wave-instr
        return;
    }

    // ---- compress: m-tile = 32 bs-rows x 64 out-k; 4 waves of 16x32 ----
    int w    = tid >> 6, lane = tid & 63;
    int q    = lane >> 4, r = lane & 15;
    int lrow0 = (w & 1) * 16;                  // local row base of this wave
    int col0  = (w >> 1) * 32;
    int row0  = bx * 32 + lrow0;               // global bs row base

    f32x4 acc0 = {0.f,0.f,0.f,0.f}, acc1 = {0.f,0.f,0.f,0.f};
    const float* arow  = Xs + (size_t)(row0 + r) * D_;        // A: bs row
    const float* brow0 = W  + (size_t)(col0 + r) * D_;        // B: out-k rows
    const float* brow1 = W  + (size_t)(col0 + 16 + r) * D_;
    const float4 z4 = {0.f,0.f,0.f,0.f};

#pragma unroll
    for (int ks = 0; ks < 10; ++ks) {
        int k0 = ks * 32 + q * 8;
        float4 a0 = (k0     < D_) ? *(const float4*)(arow  + k0)     : z4;
        float4 a1 = (k0 + 4 < D_) ? *(const float4*)(arow  + k0 + 4) : z4;
        float4 b0 = (k0     < D_) ? *(const float4*)(brow0 + k0)     : z4;
        float4 b1 = (k0 + 4 < D_) ? *(const float4*)(brow0 + k0 + 4) : z4;
        float4 c0 = (k0     < D_) ? *(const float4*)(brow1 + k0)     : z4;
        float4 c1 = (k0 + 4 < D_) ? *(const float4*)(brow1 + k0 + 4) : z4;
        union { unsigned short us[8]; s8b v; } pa, pb, pc;
        pa.us[0]=bf16_bits(a0.x); pa.us[1]=bf16_bits(a0.y);
        pa.us[2]=bf16_bits(a0.z); pa.us[3]=bf16_bits(a0.w);
        pa.us[4]=bf16_bits(a1.x); pa.us[5]=bf16_bits(a1.y);
        pa.us[6]=bf16_bits(a1.z); pa.us[7]=bf16_bits(a1.w);
        pb.us[0]=bf16_bits(b0.x); pb.us[1]=bf16_bits(b0.y);
        pb.us[2]=bf16_bits(b0.z); pb.us[3]=bf16_bits(b0.w);
        pb.us[4]=bf16_bits(b1.x); pb.us[5]=bf16_bits(b1.y);
        pb.us[6]=bf16_bits(b1.z); pb.us[7]=bf16_bits(b1.w);
        pc.us[0]=bf16_bits(c0.x); pc.us[1]=bf16_bits(c0.y);
        pc.us[2]=bf16_bits(c0.z); pc.us[3]=bf16_bits(c0.w);
        pc.us[4]=bf16_bits(c1.x); pc.us[5]=bf16_bits(c1.y);
        pc.us[6]=bf16_bits(c1.z); pc.us[7]=bf16_bits(c1.w);
        acc0 = MFMA16(pa.v, pb.v, acc0);       // cols col0+0..15
        acc1 = MFMA16(pa.v, pc.v, acc1);       // cols col0+16..31
    }
    // C/D layout: col = lane&15 (out-k), row = quad*4 + i (bs).  Write the
    // 16x32 tile (+bias, bf16-rounded) into the padded LDS transpose buffer.
#pragma unroll
    for (int i = 0; i < 4; ++i) {
        int lr = lrow0 + q * 4 + i;
        int c0i = col0 + r;
        lt[lr * LT + c0i]      = __float2bfloat16(acc0[i] + bias[c0i]);
        lt[lr * LT + c0i + 16] = __float2bfloat16(acc1[i] + bias[c0i + 16]);
    }
    __syncthreads();
    // Re-read as fragment chunks and store coalesced: thread tid = chunk
    // (ks = tid>>6, half = (tid>>5)&1, l31 = tid&31) -> XcF[bx*256 + tid].
    {
        int l31 = tid & 31, hf = (tid >> 5) & 1, ks = tid >> 6;
        uint4 ch = *(const uint4*)(&lt[l31 * LT + ks * 16 + hf * 8]);
        ((uint4*)XcF)[bx * 256 + tid] = ch;    // fully contiguous per wave
    }
}

// ---------------------------------------------------------------------------
// Kernel 2 (k_fused): bipartite GEMM + relu + max-over-n + sum-over-s.
// Explicit 2-stage SOFTWARE PIPELINE to break the per-iteration convoy:
// B-fragment registers ping-pong (bfA/bfB) so the loads for mt+1 and mt+2
// issue BEFORE the MFMAs that consume mt (fine-grained vmcnt, no vmcnt(0)
// stall per iteration); the reduce trees of pair (mt,mt+1) overlap the next
// pair's loads; the two cross-half shuffles issue back-to-back (pipelined
// DS latency, once per 2 mt).  Registers held ~<=128 so launch_bounds(256,4)
// keeps 4 waves/SIMD; grid 1024 = 4 blocks/CU, all resident, zero tail.
// NO LDS, NO BARRIERS, NO ATOMICS.  Frag-major layouts: every fragment load
// is one dwordx4 over 1024 contiguous bytes; a block's 4 waves read the same
// XcF slice in near-lockstep -> L1 dedupes.
// 32x32x16 MFMA, A = H (n rows), B = Xc (bs cols):
//   C col = lane&31 = bs, row = (reg&3)+8*(reg>>2)+4*(lane>>5) = n.
// XCD swizzle: batch = (bx&7)*2 + ((bx>>3)&1) keeps one batch's readers on
// one XCD's L2.  Grid: 16 batches x 64 o-quads = 1024 blocks.
// ---------------------------------------------------------------------------
__global__ __launch_bounds__(256, 4) void k_fused(
        const __hip_bfloat16* __restrict__ XcF,
        const __hip_bfloat16* __restrict__ HbF,
        float* __restrict__ out) {
    int tid   = threadIdx.x;
    int w     = tid >> 6, lane = tid & 63;
    int bx    = blockIdx.x;
    int batch = (bx & 7) * 2 + ((bx >> 3) & 1);   // XCD-local batches
    int og    = bx >> 4;          // 0..63 : o-quad
    int o     = og * 4 + w;       // this wave's output

    const uint4* hb = (const uint4*)HbF;
    const uint4* xf = (const uint4*)XcF + (size_t)batch * (32 * 256) + lane;

    // A fragments: 2 n-tiles x 4 k-steps, each a contiguous 1KB load (32 VGPR).
    s8b af[2][4];
#pragma unroll
    for (int nt = 0; nt < 2; ++nt)
#pragma unroll
        for (int ks = 0; ks < 4; ++ks)
            af[nt][ks] = __builtin_bit_cast(s8b,
                hb[o * 512 + nt * 256 + ks * 64 + lane]);

    const f32x16 kZero = {0.f,0.f,0.f,0.f,0.f,0.f,0.f,0.f,
                          0.f,0.f,0.f,0.f,0.f,0.f,0.f,0.f};

    // Pipeline prologue: load mt=0 into bfA.
    s8b bfA[4], bfB[4];
#pragma unroll
    for (int ks = 0; ks < 4; ++ks)
        bfA[ks] = __builtin_bit_cast(s8b, xf[ks * 64]);

    float total = 0.0f;
    for (int mt = 0; mt < 32; mt += 2) {
        // Prefetch odd tile (mt+1) -> bfB.
#pragma unroll
        for (int ks = 0; ks < 4; ++ks)
            bfB[ks] = __builtin_bit_cast(s8b, xf[(mt + 1) * 256 + ks * 64]);

        // MFMA burst on even tile (bfA): two independent 4-chains.
        f32x16 a0 = MFMA32(af[0][0], bfA[0], kZero);
        f32x16 a1 = MFMA32(af[1][0], bfA[0], kZero);
#pragma unroll
        for (int ks = 1; ks < 4; ++ks) {
            a0 = MFMA32(af[0][ks], bfA[ks], a0);
            a1 = MFMA32(af[1][ks], bfA[ks], a1);
        }
        // Reduce even tile (frees a0/a1; overlaps the next prefetch below).
        float uA0 = max3f(a0[0],  a0[1],  a0[2]);
        float uA1 = max3f(a0[3],  a0[4],  a0[5]);
        float uA2 = max3f(a0[6],  a0[7],  a0[8]);
        float uA3 = max3f(a0[9],  a0[10], a0[11]);
        float uA4 = max3f(a0[12], a0[13], a0[14]);
        float uA5 = max3f(a1[0],  a1[1],  a1[2]);
        float uA6 = max3f(a1[3],  a1[4],  a1[5]);
        float uA7 = max3f(a1[6],  a1[7],  a1[8]);
        float uA8 = max3f(a1[9],  a1[10], a1[11]);
        float uA9 = max3f(a1[12], a1[13], a1[14]);
        float tA0 = max3f(uA0, uA1, uA2);
        float tA1 = max3f(uA3, uA4, uA5);
        float tA2 = max3f(uA6, uA7, uA8);
        float tA3 = max3f(uA9, a0[15], a1[15]);
        float vA  = fmaxf(fmaxf(tA0, tA1), fmaxf(tA2, tA3));

        // Prefetch next even tile ((mt+2)&31 -> wraps to 0 on last iter,
        // branchless; the redundant final load is harmless).
#pragma unroll
        for (int ks = 0; ks < 4; ++ks)
            bfA[ks] = __builtin_bit_cast(s8b, xf[((mt + 2) & 31) * 256 + ks * 64]);

        // MFMA burst on odd tile (bfB).
        f32x16 b0 = MFMA32(af[0][0], bfB[0], kZero);
        f32x16 b1 = MFMA32(af[1][0], bfB[0], kZero);
#pragma unroll
        for (int ks = 1; ks < 4; ++ks) {
            b0 = MFMA32(af[0][ks], bfB[ks], b0);
            b1 = MFMA32(af[1][ks], bfB[ks], b1);
        }
        float uB0 = max3f(b0[0],  b0[1],  b0[2]);
        float uB1 = max3f(b0[3],  b0[4],  b0[5]);
        float uB2 = max3f(b0[6],  b0[7],  b0[8]);
        float uB3 = max3f(b0[9],  b0[10], b0[11]);
        float uB4 = max3f(b0[12], b0[13], b0[14]);
        float uB5 = max3f(b1[0],  b1[1],  b1[2]);
        float uB6 = max3f(b1[3],  b1[4],  b1[5]);
        float uB7 = max3f(b1[6],  b1[7],  b1[8]);
        float uB8 = max3f(b1[9],  b1[10], b1[11]);
        float uB9 = max3f(b1[12], b1[13], b1[14]);
        float tB0 = max3f(uB0, uB1, uB2);
        float tB1 = max3f(uB3, uB4, uB5);
        float tB2 = max3f(uB6, uB7, uB8);
        float tB3 = max3f(uB9, b0[15], b1[15]);
        float vB  = fmaxf(fmaxf(tB0, tB1), fmaxf(tB2, tB3));

        // Batched cross-half merges: two back-to-back shuffles pipeline.
        float sA = __shfl_xor(vA, 32);
        float sB = __shfl_xor(vB, 32);
        total += fmaxf(fmaxf(vA, sA), 0.0f);   // relu folded into max
        total += fmaxf(fmaxf(vB, sB), 0.0f);
    }
    // Sum the 32 bs columns (both halves hold identical totals).
    total += __shfl_xor(total, 1);
    total += __shfl_xor(total, 2);
    total += __shfl_xor(total, 4);
    total += __shfl_xor(total, 8);
    total += __shfl_xor(total, 16);
    if (lane == 0) out[batch * O_ + o] = total;   // plain store
}

// ---------------------------------------------------------------------------
extern "C" void kernel_launch(void* const* d_in, const int* in_sizes, int n_in,
                              void* d_out, int out_size, void* d_ws, size_t ws_size,
                              hipStream_t stream) {
    const float* Xs   = (const float*)d_in[0];   // [16,1024,300]
    const float* W    = (const float*)d_in[1];   // [64,300]
    const float* bias = (const float*)d_in[2];   // [64]
    const float* H    = (const float*)d_in[3];   // [256,64,64]
    float* out = (float*)d_out;                  // [16,256] f32

    char* ws = (char*)d_ws;
    __hip_bfloat16* HbF = (__hip_bfloat16*)(ws);              // 2,097,152 B
    __hip_bfloat16* XcF = (__hip_bfloat16*)(ws + 2097152);    // 2,097,152 B

    k_prep <<<C_BLK + H_BLK, 256, 0, stream>>>(Xs, W, bias, H, XcF, HbF);
    k_fused<<<B_ * (O_ / 4), 256, 0, stream>>>(XcF, HbF, out);
}